// Round 10
// baseline (159.233 us; speedup 1.0000x reference)
//
#include <hip/hip_runtime.h>

#define N 1024
#define THREADS 256
#define EPT 4  // fallback path

// ---------------------------------------------------------------------------
// Shared pass pipeline (fallback path only, known correct).
// ---------------------------------------------------------------------------
__device__ __forceinline__ float2* run_pipeline(
    float2* bufA, float2* bufB, int tid,
    const float* __restrict__ logits,
    const float* __restrict__ diags,
    const float* __restrict__ subd,
    const float* __restrict__ supd)
{
    float2* src = bufA;
    float2* dst = bufB;

    for (int d = 0; d < 2; ++d) {
        for (int j = 0; j < 9; ++j) {
            const int s = 4 << j;
            const int h = s >> 1;
            const float* lg = logits + (d * 9 + j) * 3;
            const float p0 = 1.0f / (1.0f + expf(-lg[0]));
            const float p1 = 1.0f / (1.0f + expf(-lg[1]));
            const float p2 = 1.0f / (1.0f + expf(-lg[2]));
#pragma unroll
            for (int e = 0; e < EPT; ++e) {
                const int idx = tid + e * THREADS;
                const int base = idx & ~(s - 1);
                const int t = idx & (s - 1);
                const bool lo = (t < h);

                const int eo_t = lo ? (2 * t) : (2 * (t - h) + 1);
                const float2 xt  = src[idx];
                const float2 xeo = src[base + eo_t];
                float2 yt;
                yt.x = xt.x + p0 * (xeo.x - xt.x);
                yt.y = xt.y + p0 * (xeo.y - xt.y);

                const int tm = lo ? (h - 1 - t) : (s + h - 1 - t);
                const float psel = lo ? p1 : p2;
                const int eo_m = (tm < h) ? (2 * tm) : (2 * (tm - h) + 1);
                const float2 xm   = src[base + tm];
                const float2 xmeo = src[base + eo_m];
                float2 ym;
                ym.x = xm.x + p0 * (xmeo.x - xm.x);
                ym.y = xm.y + p0 * (xmeo.y - xm.y);

                float2 o;
                o.x = yt.x + psel * (ym.x - yt.x);
                o.y = yt.y + psel * (ym.y - yt.y);
                dst[idx] = o;
            }
            __syncthreads();
            float2* tmp = src; src = dst; dst = tmp;
        }
        for (int i = 0; i < 10; ++i) {
            const int k = N >> (i + 1);
            const float2* Dg = (const float2*)(diags + (size_t)((d * 10 + i) * N) * 2);
            const float2* Sb = (const float2*)(subd  + (size_t)((d * 10 + i) * N) * 2);
            const float2* Sp = (const float2*)(supd  + (size_t)((d * 10 + i) * N) * 2);
#pragma unroll
            for (int e = 0; e < EPT; ++e) {
                const int idx = tid + e * THREADS;
                const float2 xv = src[idx];
                const float2 dg = Dg[idx];
                float2 o;
                o.x = dg.x * xv.x - dg.y * xv.y;
                o.y = dg.x * xv.y + dg.y * xv.x;
                if (idx >= k) {
                    const float2 xs = src[idx - k];
                    const float2 sb = Sb[idx - k];
                    o.x += sb.x * xs.x - sb.y * xs.y;
                    o.y += sb.x * xs.y + sb.y * xs.x;
                }
                if (idx < N - k) {
                    const float2 xp = src[idx + k];
                    const float2 sp = Sp[idx];
                    o.x += sp.x * xp.x - sp.y * xp.y;
                    o.y += sp.x * xp.y + sp.y * xp.x;
                }
                dst[idx] = o;
            }
            __syncthreads();
            float2* tmp = src; src = dst; dst = tmp;
        }
    }
    return src;
}

// ---------------------------------------------------------------------------
// Fallback: direct per-row kernel (round-1, known correct).
// ---------------------------------------------------------------------------
__global__ __launch_bounds__(THREADS) void trifat_kernel_impl(
    const float* __restrict__ x,
    const float* __restrict__ logits,
    const float* __restrict__ diags,
    const float* __restrict__ subd,
    const float* __restrict__ supd,
    const float* __restrict__ bias,
    float* __restrict__ out,
    int B)
{
    __shared__ float2 bufA[N];
    __shared__ float2 bufB[N];

    const int row = blockIdx.x;
    const int tid = threadIdx.x;
    if (row >= B) return;

    const float* xr = x + (size_t)row * N;
#pragma unroll
    for (int e = 0; e < EPT; ++e) {
        int idx = tid + e * THREADS;
        bufA[idx] = make_float2(xr[idx], 0.0f);
    }
    __syncthreads();

    float2* res = run_pipeline(bufA, bufB, tid, logits, diags, subd, supd);

    float* orow = out + (size_t)row * N;
#pragma unroll
    for (int e = 0; e < EPT; ++e) {
        int idx = tid + e * THREADS;
        orow[idx] = res[idx].x + bias[idx];
    }
}

// ---------------------------------------------------------------------------
// bf16 helper
// ---------------------------------------------------------------------------
__device__ __forceinline__ unsigned short f2bf_rne(float f) {
    unsigned int u = __float_as_uint(f);
    unsigned int r = u + 0x7fffu + ((u >> 16) & 1u);
    return (unsigned short)(r >> 16);
}

// paired complex multiply-accumulate on float4 = 2 complex
__device__ __forceinline__ void cmac4(float4& o, const float4 c, const float4 x) {
    o.x += c.x * x.x - c.y * x.y;
    o.y += c.x * x.y + c.y * x.x;
    o.z += c.z * x.z - c.w * x.w;
    o.w += c.z * x.w + c.w * x.z;
}

// ---------------------------------------------------------------------------
// Fused prep kernel — round-21 = round-20 base (best total, 122.2) with
// MERGED BUTTERFLY PAIRS:
//   8 rounds showed per-pass-slot time (~1.2 us) is invariant to VALU
//   content, barrier type, occupancy, and phasing -> the only lever left is
//   the NUMBER of slots. Consecutive butterflies have k1 = 2*k2, so B∘A is
//   a 7-tap operator computable in ONE LDS round trip:
//     y[g] = DB[g]*u(g) + SbB[g-GB]*u(g-GB) + SpB[g]*u(g+GB),
//   where u(q) re-evaluates pass A at group q (3 cmads, same guard
//   structure as the verified per-pass code; all offsets stay even at
//   group granularity). Merged pairs: (512,256),(128,64),(32,16),(8,4).
//   k=2 and k=1 stay unmerged (k2=1 odd breaks float4 alignment).
//   Passes/depth 19 -> 15; total 38 -> 30.
//   (kept from r20: sigmoid hoist, wave-local s<=128 perms + jp==6 fence,
//   cohort jitter, depth-0 sparsity.)
//  blocks [0,512):   build 2 basis-vector images -> scatter Bt bf16
//  blocks [512,768): conv x -> A2 bf16
// ---------------------------------------------------------------------------
#define TBW 512
#define NB_BUILD 512

__global__ __launch_bounds__(TBW) void prep_kernel(
    const float* __restrict__ logits,
    const float* __restrict__ diags,
    const float* __restrict__ subd,
    const float* __restrict__ supd,
    const float* __restrict__ x,
    unsigned short* __restrict__ Bt,   // [1024][1024] bf16, Bt[n][j]
    unsigned short* __restrict__ A2)   // [B][1024] bf16
{
    __shared__ __align__(16) float2 buf[2][2][N];  // [buffer][vector][pos], 32 KB
    __shared__ float sig[54];

    const int tid = threadIdx.x;

    if (blockIdx.x >= NB_BUILD) {
        // ---------------- conv role ----------------
        const int cb = blockIdx.x - NB_BUILD;        // 0..255
        const size_t base4 = (size_t)cb * 4096;      // float4 index base
#pragma unroll
        for (int r = 0; r < 8; ++r) {
            const size_t g4 = base4 + r * 512 + tid;
            const float4 v = *(const float4*)(x + g4 * 4);
            ushort4 o;
            o.x = f2bf_rne(v.x);
            o.y = f2bf_rne(v.y);
            o.z = f2bf_rne(v.z);
            o.w = f2bf_rne(v.w);
            *(ushort4*)(A2 + g4 * 4) = o;
        }
        return;
    }

    // ---- cohort de-phase: second resident cohort starts ~half a pass late
    if (blockIdx.x & 256) {
        unsigned long long t0 = __builtin_amdgcn_s_memrealtime();
        while (__builtin_amdgcn_s_memrealtime() - t0 < 64ULL) { }
    }

    // ---------------- build role ----------------
    const int j0 = blockIdx.x * 2;
    const int t = tid;

    // zero-init BOTH buffers (required by depth-0 sparse perms) + sig table
#pragma unroll
    for (int b = 0; b < 2; ++b)
#pragma unroll
        for (int v = 0; v < 2; ++v)
#pragma unroll
            for (int e = 0; e < 2; ++e)
                buf[b][v][tid + e * TBW] = make_float2(0.0f, 0.0f);
    if (tid < 54) sig[tid] = 1.0f / (1.0f + __expf(-logits[tid]));
    __syncthreads();
    if (tid < 2) buf[0][tid][j0 + tid] = make_float2(1.0f, 0.0f);
    __syncthreads();

    int sb = 0;
    for (int d = 0; d < 2; ++d) {
        // ---- 9 perm passes; s<=128 wave-local barrier-free, s>=256 r12 ----
        for (int jp = 0; jp < 9; ++jp) {
            const int s = 4 << jp;
            const int h = s >> 1;
            const int hh = s >> 2;
            const float p0 = sig[(d * 9 + jp) * 3 + 0];
            const float p1 = sig[(d * 9 + jp) * 3 + 1];
            const float p2 = sig[(d * 9 + jp) * 3 + 2];

            // shared mirror-pair body
            auto permTask = [&](int wt, int base) {
                int tt, tm;
                float psel;
                if (wt < hh) { tt = wt;              tm = h - 1 - wt;  psel = p1; }
                else         { const int u = wt - hh; tt = h + u; tm = s - 1 - u; psel = p2; }

                const int eot = (tt < h) ? (2 * tt) : (2 * (tt - h) + 1);
                const int eom = (tm < h) ? (2 * tm) : (2 * (tm - h) + 1);

#pragma unroll
                for (int v = 0; v < 2; ++v) {
                    const float2* src = buf[sb][v];
                    float2* dst = buf[sb ^ 1][v];

                    const float2 xt = src[base + tt], xet = src[base + eot];
                    const float2 xm = src[base + tm], xem = src[base + eom];
                    float2 yt, ym;
                    yt.x = xt.x + p0 * (xet.x - xt.x);
                    yt.y = xt.y + p0 * (xet.y - xt.y);
                    ym.x = xm.x + p0 * (xem.x - xm.x);
                    ym.y = xm.y + p0 * (xem.y - xm.y);

                    float2 ot, om;
                    ot.x = yt.x + psel * (ym.x - yt.x);
                    ot.y = yt.y + psel * (ym.y - yt.y);
                    om.x = ym.x + psel * (yt.x - ym.x);
                    om.y = ym.y + psel * (yt.y - ym.y);
                    dst[base + tt] = ot;
                    dst[base + tm] = om;
                }
            };

            if (jp <= 5) {
                // ---- s <= 128: one wave owns each 128-chunk (both cols) ----
                const int wv = tid >> 6;
                const int lane = tid & 63;
                if (d == 0) {
                    // sparse: active chunk = the one containing j0 (j0,j0+1 same chunk)
                    if (wv == (j0 >> 7) && lane < h) {
                        permTask(lane, (j0 >> (jp + 2)) << (jp + 2));
                    }
                } else {
                    // dense: 64 tasks per chunk (one per lane)
                    permTask(lane & (h - 1),
                             128 * wv + ((lane >> (jp + 1)) << (jp + 2)));
                }
                // intra-wave ordering only: DS writes retired -> visible to wave
                asm volatile("s_waitcnt lgkmcnt(0)" ::: "memory");
                sb ^= 1;
            } else {
                // ---- s >= 256: original r12 mapping + barrier ----
                // FENCE (r5 bug fix): jp==6 reads across 128-chunks written
                // by OTHER waves in the barrier-free jp<=5 section.
                if (jp == 6) __syncthreads();

                int w = -1, base = 0;
                if (d == 0) {
                    if (tid < h) {
                        w = tid;
                        base = (j0 >> (jp + 2)) << (jp + 2);
                    }
                } else {
                    w = tid & (h - 1);
                    base = (tid >> (jp + 1)) << (jp + 2);
                }
                if (w >= 0) permTask(w, base);
                __syncthreads();
                sb ^= 1;
            }
        }

        // ---- 4 MERGED butterfly pairs: (k1,k2) = (512,256),(128,64),
        //      (32,16),(8,4). One LDS round trip per pair. ----
        for (int m = 0; m < 4; ++m) {
            const int iA = d * 10 + 2 * m;
            const int k1 = N >> (2 * m + 1);      // 512,128,32,8
            const int GA = k1 >> 1;               // A group shift: 256,64,16,4
            const int GB = k1 >> 2;               // B group shift: 128,32,8,2
            const float4* DgA = (const float4*)(diags + (size_t)(iA * N) * 2);
            const float4* SbA = (const float4*)(subd  + (size_t)(iA * N) * 2);
            const float4* SpA = (const float4*)(supd  + (size_t)(iA * N) * 2);
            const float4* DgB = (const float4*)(diags + (size_t)((iA + 1) * N) * 2);
            const float4* SbB = (const float4*)(subd  + (size_t)((iA + 1) * N) * 2);
            const float4* SpB = (const float4*)(supd  + (size_t)((iA + 1) * N) * 2);

#pragma unroll
            for (int v = 0; v < 2; ++v) {
                const float2* srcv = buf[sb][v];

                // evaluate pass A (offset k1) at group gq — guards identical
                // in structure to the verified unmerged pass
                auto u4 = [&](int gq) -> float4 {
                    const float4 xv = *(const float4*)(&srcv[2 * gq]);
                    const float4 dA = DgA[gq];
                    float4 u;
                    u.x = dA.x * xv.x - dA.y * xv.y;
                    u.y = dA.x * xv.y + dA.y * xv.x;
                    u.z = dA.z * xv.z - dA.w * xv.w;
                    u.w = dA.z * xv.w + dA.w * xv.z;
                    if (gq >= GA) {
                        const float4 xs = *(const float4*)(&srcv[2 * (gq - GA)]);
                        cmac4(u, SbA[gq - GA], xs);
                    }
                    if (gq < 512 - GA) {
                        const float4 xp = *(const float4*)(&srcv[2 * (gq + GA)]);
                        cmac4(u, SpA[gq], xp);
                    }
                    return u;
                };

                const float4 uc = u4(t);
                const float4 dB = DgB[t];
                float4 y;
                y.x = dB.x * uc.x - dB.y * uc.y;
                y.y = dB.x * uc.y + dB.y * uc.x;
                y.z = dB.z * uc.z - dB.w * uc.w;
                y.w = dB.z * uc.w + dB.w * uc.z;
                if (t >= GB)       cmac4(y, SbB[t - GB], u4(t - GB));
                if (t < 512 - GB)  cmac4(y, SpB[t],      u4(t + GB));
                *(float4*)(&buf[sb ^ 1][v][2 * t]) = y;
            }
            __syncthreads();
            sb ^= 1;
        }

        // ---- k = 2 paired pass (unmerged; group shift 1) ----
        {
            const int i = d * 10 + 8;
            const float4* Dg4 = (const float4*)(diags + (size_t)(i * N) * 2);
            const float4* Sb4 = (const float4*)(subd  + (size_t)(i * N) * 2);
            const float4* Sp4 = (const float4*)(supd  + (size_t)(i * N) * 2);
            const bool has_sb = (t >= 1);
            const bool has_sp = (t < 511);
            const float4 dg4 = Dg4[t];
            const float4 sb4 = has_sb ? Sb4[t - 1] : make_float4(0.f, 0.f, 0.f, 0.f);
            const float4 sp4 = has_sp ? Sp4[t]     : make_float4(0.f, 0.f, 0.f, 0.f);
#pragma unroll
            for (int v = 0; v < 2; ++v) {
                const float2* src = buf[sb][v];
                const float4 xv = *(const float4*)(&src[2 * t]);
                float4 o;
                o.x = dg4.x * xv.x - dg4.y * xv.y;
                o.y = dg4.x * xv.y + dg4.y * xv.x;
                o.z = dg4.z * xv.z - dg4.w * xv.w;
                o.w = dg4.z * xv.w + dg4.w * xv.z;
                if (has_sb) {
                    const float4 xs = *(const float4*)(&src[2 * t - 2]);
                    cmac4(o, sb4, xs);
                }
                if (has_sp) {
                    const float4 xp = *(const float4*)(&src[2 * t + 2]);
                    cmac4(o, sp4, xp);
                }
                *(float4*)(&buf[sb ^ 1][v][2 * t]) = o;
            }
            __syncthreads();
            sb ^= 1;
        }

        // ---- k = 1 scalar pass ----
        {
            const float2* Dg = (const float2*)(diags + (size_t)((d * 10 + 9) * N) * 2);
            const float2* Sb = (const float2*)(subd  + (size_t)((d * 10 + 9) * N) * 2);
            const float2* Sp = (const float2*)(supd  + (size_t)((d * 10 + 9) * N) * 2);
            const int i0 = 2 * t, i1 = 2 * t + 1;
            const float2 dg0 = Dg[i0], dg1 = Dg[i1];
            const float2 sb0 = (t >= 1) ? Sb[i0 - 1] : make_float2(0.f, 0.f);
            const float2 sb1 = Sb[i0];
            const float2 sp0 = Sp[i0];
            const float2 sp1 = (t < 511) ? Sp[i1] : make_float2(0.f, 0.f);
#pragma unroll
            for (int v = 0; v < 2; ++v) {
                const float2* src = buf[sb][v];
                const float2 x0 = src[i0], x1 = src[i1];
                float2 o0, o1;
                o0.x = dg0.x * x0.x - dg0.y * x0.y;
                o0.y = dg0.x * x0.y + dg0.y * x0.x;
                o1.x = dg1.x * x1.x - dg1.y * x1.y;
                o1.y = dg1.x * x1.y + dg1.y * x1.x;
                if (t >= 1) {
                    const float2 xs = src[i0 - 1];
                    o0.x += sb0.x * xs.x - sb0.y * xs.y;
                    o0.y += sb0.x * xs.y + sb0.y * xs.x;
                }
                // i1 >= 1 always: sub term for o1 uses src[i0] = x0
                o1.x += sb1.x * x0.x - sb1.y * x0.y;
                o1.y += sb1.x * x0.y + sb1.y * x0.x;
                // i0 < 1023 always: sup term for o0 uses src[i1] = x1
                o0.x += sp0.x * x1.x - sp0.y * x1.y;
                o0.y += sp0.x * x1.y + sp0.y * x1.x;
                if (t < 511) {
                    const float2 xp = src[i1 + 1];
                    o1.x += sp1.x * xp.x - sp1.y * xp.y;
                    o1.y += sp1.x * xp.y + sp1.y * xp.x;
                }
                float4 ow;
                ow.x = o0.x; ow.y = o0.y; ow.z = o1.x; ow.w = o1.y;
                *(float4*)(&buf[sb ^ 1][v][i0]) = ow;
            }
            __syncthreads();
            sb ^= 1;
        }
    }

    // ---- epilogue: scatter-write transposed bf16 directly: Bt[n][j0+v] ----
#pragma unroll
    for (int v = 0; v < 2; ++v)
#pragma unroll
        for (int e = 0; e < 2; ++e) {
            const int idx = tid + e * TBW;
            Bt[(size_t)idx * N + (j0 + v)] = f2bf_rne(buf[sb][v][idx].x);
        }
}

// ---------------------------------------------------------------------------
// GEMM round-14 (best measured config): BM=128 x BN=64, BK=64, serial
// 2-barrier K-loop, grid (32,16)=512 blocks -> 2 blocks/CU, XOR-swizzled LDS.
// ---------------------------------------------------------------------------
typedef __attribute__((ext_vector_type(8))) __bf16 bf16x8;
typedef __attribute__((ext_vector_type(4))) float f32x4;

#define GLB(p) ((const __attribute__((address_space(1))) void*)(p))
#define LDS(p) ((__attribute__((address_space(3))) void*)(p))

__global__ __launch_bounds__(THREADS) void gemm_bf16(
    const unsigned short* __restrict__ A2,  // [B][1024] bf16
    const unsigned short* __restrict__ Bt,  // [1024][1024] bf16
    const float* __restrict__ bias,
    float* __restrict__ out)
{
    __shared__ __align__(16) unsigned short As[128 * 64];   // 16 KB
    __shared__ __align__(16) unsigned short Bs[64 * 64];    // 8 KB

    const int m0 = blockIdx.x * 128;
    const int n0 = blockIdx.y * 64;
    const int tid = threadIdx.x;
    const int wave = tid >> 6, lane = tid & 63;
    const int wm = (wave >> 1) * 64, wn = (wave & 1) * 32;
    const int lrow = lane & 15, q = lane >> 4;
    const int r7 = lrow & 7;

    f32x4 acc[4][2] = {};

    for (int kt = 0; kt < 16; ++kt) {
        const int k0 = kt * 64;
        __syncthreads();  // previous tile fully consumed
        {
            const unsigned short* gA = A2 + (size_t)m0 * N + k0;
            const unsigned short* gB = Bt + (size_t)n0 * N + k0;
#pragma unroll
            for (int r = 0; r < 4; ++r) {           // A: 128 rows x 8 groups
                const int s = r * 256 + tid;
                const int row = s >> 3;
                const int gl = (s & 7) ^ (row & 7);  // XOR-swizzled k-group
                __builtin_amdgcn_global_load_lds(GLB(gA + (size_t)row * N + gl * 8),
                                                 LDS(As + s * 8), 16, 0, 0);
            }
#pragma unroll
            for (int r = 0; r < 2; ++r) {           // B: 64 rows x 8 groups
                const int s = r * 256 + tid;
                const int row = s >> 3;
                const int gl = (s & 7) ^ (row & 7);
                __builtin_amdgcn_global_load_lds(GLB(gB + (size_t)row * N + gl * 8),
                                                 LDS(Bs + s * 8), 16, 0, 0);
            }
        }
        __syncthreads();  // DMA drained -> tile ready

#pragma unroll
        for (int kk = 0; kk < 64; kk += 32) {
            const int pg = ((kk >> 3) + q) ^ r7;  // physical (swizzled) group
            bf16x8 a[4], b[2];
#pragma unroll
            for (int mi = 0; mi < 4; ++mi)
                a[mi] = *(const bf16x8*)(As + (wm + mi * 16 + lrow) * 64 + pg * 8);
#pragma unroll
            for (int ni = 0; ni < 2; ++ni)
                b[ni] = *(const bf16x8*)(Bs + (wn + ni * 16 + lrow) * 64 + pg * 8);
#pragma unroll
            for (int mi = 0; mi < 4; ++mi)
#pragma unroll
                for (int ni = 0; ni < 2; ++ni)
                    acc[mi][ni] = __builtin_amdgcn_mfma_f32_16x16x32_bf16(
                        a[mi], b[ni], acc[mi][ni], 0, 0, 0);
        }
    }

    // epilogue: C/D layout col=lane&15, row=q*4+reg
#pragma unroll
    for (int ni = 0; ni < 2; ++ni) {
        const int col = n0 + wn + ni * 16 + lrow;
        const float bv = bias[col];
#pragma unroll
        for (int mi = 0; mi < 4; ++mi)
#pragma unroll
            for (int r = 0; r < 4; ++r) {
                const int row = m0 + wm + mi * 16 + q * 4 + r;
                out[(size_t)row * N + col] = acc[mi][ni][r] + bv;
            }
    }
}

// ---------------------------------------------------------------------------
extern "C" void kernel_launch(void* const* d_in, const int* in_sizes, int n_in,
                              void* d_out, int out_size, void* d_ws, size_t ws_size,
                              hipStream_t stream) {
    const float* x      = (const float*)d_in[0];
    const float* logits = (const float*)d_in[1];
    const float* diags  = (const float*)d_in[2];
    const float* subd   = (const float*)d_in[3];
    const float* supd   = (const float*)d_in[4];
    const float* bias   = (const float*)d_in[5];
    float* out = (float*)d_out;

    const int B = in_sizes[0] / N;  // 4096

    const size_t off_Bt = 0;                                // Bt: 1024*1024*2 B
    const size_t off_A2 = 2u * 1024 * 1024;
    const size_t need   = off_A2 + (size_t)B * N * 2;       // A2: B*1024*2 B

    if (ws_size >= need && B == 4096) {
        unsigned short* Bt = (unsigned short*)((char*)d_ws + off_Bt);
        unsigned short* A2 = (unsigned short*)((char*)d_ws + off_A2);

        prep_kernel<<<dim3(NB_BUILD + 256), dim3(TBW), 0, stream>>>(
            logits, diags, subd, supd, x, Bt, A2);
        gemm_bf16<<<dim3(B / 128, 16), dim3(THREADS), 0, stream>>>(A2, Bt, bias, out);
    } else {
        trifat_kernel_impl<<<dim3(B), dim3(THREADS), 0, stream>>>(
            x, logits, diags, subd, supd, bias, out, B);
    }
}

// Round 11
// 120.491 us; speedup vs baseline: 1.3215x; 1.3215x over previous
//
#include <hip/hip_runtime.h>

#define N 1024
#define THREADS 256
#define EPT 4  // fallback path

// ---------------------------------------------------------------------------
// Shared pass pipeline (fallback path only, known correct).
// ---------------------------------------------------------------------------
__device__ __forceinline__ float2* run_pipeline(
    float2* bufA, float2* bufB, int tid,
    const float* __restrict__ logits,
    const float* __restrict__ diags,
    const float* __restrict__ subd,
    const float* __restrict__ supd)
{
    float2* src = bufA;
    float2* dst = bufB;

    for (int d = 0; d < 2; ++d) {
        for (int j = 0; j < 9; ++j) {
            const int s = 4 << j;
            const int h = s >> 1;
            const float* lg = logits + (d * 9 + j) * 3;
            const float p0 = 1.0f / (1.0f + expf(-lg[0]));
            const float p1 = 1.0f / (1.0f + expf(-lg[1]));
            const float p2 = 1.0f / (1.0f + expf(-lg[2]));
#pragma unroll
            for (int e = 0; e < EPT; ++e) {
                const int idx = tid + e * THREADS;
                const int base = idx & ~(s - 1);
                const int t = idx & (s - 1);
                const bool lo = (t < h);

                const int eo_t = lo ? (2 * t) : (2 * (t - h) + 1);
                const float2 xt  = src[idx];
                const float2 xeo = src[base + eo_t];
                float2 yt;
                yt.x = xt.x + p0 * (xeo.x - xt.x);
                yt.y = xt.y + p0 * (xeo.y - xt.y);

                const int tm = lo ? (h - 1 - t) : (s + h - 1 - t);
                const float psel = lo ? p1 : p2;
                const int eo_m = (tm < h) ? (2 * tm) : (2 * (tm - h) + 1);
                const float2 xm   = src[base + tm];
                const float2 xmeo = src[base + eo_m];
                float2 ym;
                ym.x = xm.x + p0 * (xmeo.x - xm.x);
                ym.y = xm.y + p0 * (xmeo.y - xm.y);

                float2 o;
                o.x = yt.x + psel * (ym.x - yt.x);
                o.y = yt.y + psel * (ym.y - yt.y);
                dst[idx] = o;
            }
            __syncthreads();
            float2* tmp = src; src = dst; dst = tmp;
        }
        for (int i = 0; i < 10; ++i) {
            const int k = N >> (i + 1);
            const float2* Dg = (const float2*)(diags + (size_t)((d * 10 + i) * N) * 2);
            const float2* Sb = (const float2*)(subd  + (size_t)((d * 10 + i) * N) * 2);
            const float2* Sp = (const float2*)(supd  + (size_t)((d * 10 + i) * N) * 2);
#pragma unroll
            for (int e = 0; e < EPT; ++e) {
                const int idx = tid + e * THREADS;
                const float2 xv = src[idx];
                const float2 dg = Dg[idx];
                float2 o;
                o.x = dg.x * xv.x - dg.y * xv.y;
                o.y = dg.x * xv.y + dg.y * xv.x;
                if (idx >= k) {
                    const float2 xs = src[idx - k];
                    const float2 sb = Sb[idx - k];
                    o.x += sb.x * xs.x - sb.y * xs.y;
                    o.y += sb.x * xs.y + sb.y * xs.x;
                }
                if (idx < N - k) {
                    const float2 xp = src[idx + k];
                    const float2 sp = Sp[idx];
                    o.x += sp.x * xp.x - sp.y * xp.y;
                    o.y += sp.x * xp.y + sp.y * xp.x;
                }
                dst[idx] = o;
            }
            __syncthreads();
            float2* tmp = src; src = dst; dst = tmp;
        }
    }
    return src;
}

// ---------------------------------------------------------------------------
// Fallback: direct per-row kernel (round-1, known correct).
// ---------------------------------------------------------------------------
__global__ __launch_bounds__(THREADS) void trifat_kernel_impl(
    const float* __restrict__ x,
    const float* __restrict__ logits,
    const float* __restrict__ diags,
    const float* __restrict__ subd,
    const float* __restrict__ supd,
    const float* __restrict__ bias,
    float* __restrict__ out,
    int B)
{
    __shared__ float2 bufA[N];
    __shared__ float2 bufB[N];

    const int row = blockIdx.x;
    const int tid = threadIdx.x;
    if (row >= B) return;

    const float* xr = x + (size_t)row * N;
#pragma unroll
    for (int e = 0; e < EPT; ++e) {
        int idx = tid + e * THREADS;
        bufA[idx] = make_float2(xr[idx], 0.0f);
    }
    __syncthreads();

    float2* res = run_pipeline(bufA, bufB, tid, logits, diags, subd, supd);

    float* orow = out + (size_t)row * N;
#pragma unroll
    for (int e = 0; e < EPT; ++e) {
        int idx = tid + e * THREADS;
        orow[idx] = res[idx].x + bias[idx];
    }
}

// ---------------------------------------------------------------------------
// bf16 helper
// ---------------------------------------------------------------------------
__device__ __forceinline__ unsigned short f2bf_rne(float f) {
    unsigned int u = __float_as_uint(f);
    unsigned int r = u + 0x7fffu + ((u >> 16) & 1u);
    return (unsigned short)(r >> 16);
}

// ---------------------------------------------------------------------------
// Fused prep kernel — round-22 = EXACT round-8 restoration (best measured,
// 122.2 us total). r18 features: sigmoid hoist, wave-local s<=128 perms +
// jp==6 fence, depth-0 sparsity, paired butterflies, coeff prefetch,
// cohort jitter. The r10 merged-pass experiment was falsified (slot cost
// scales with per-slot traffic; occupancy halved) — reverted.
//  blocks [0,512):   build 2 basis-vector images -> scatter Bt bf16
//  blocks [512,768): conv x -> A2 bf16
// ---------------------------------------------------------------------------
#define TBW 512
#define NB_BUILD 512

__global__ __launch_bounds__(TBW) void prep_kernel(
    const float* __restrict__ logits,
    const float* __restrict__ diags,
    const float* __restrict__ subd,
    const float* __restrict__ supd,
    const float* __restrict__ x,
    unsigned short* __restrict__ Bt,   // [1024][1024] bf16, Bt[n][j]
    unsigned short* __restrict__ A2)   // [B][1024] bf16
{
    __shared__ __align__(16) float2 buf[2][2][N];  // [buffer][vector][pos], 32 KB
    __shared__ float sig[54];

    const int tid = threadIdx.x;

    if (blockIdx.x >= NB_BUILD) {
        // ---------------- conv role ----------------
        const int cb = blockIdx.x - NB_BUILD;        // 0..255
        const size_t base4 = (size_t)cb * 4096;      // float4 index base
#pragma unroll
        for (int r = 0; r < 8; ++r) {
            const size_t g4 = base4 + r * 512 + tid;
            const float4 v = *(const float4*)(x + g4 * 4);
            ushort4 o;
            o.x = f2bf_rne(v.x);
            o.y = f2bf_rne(v.y);
            o.z = f2bf_rne(v.z);
            o.w = f2bf_rne(v.w);
            *(ushort4*)(A2 + g4 * 4) = o;
        }
        return;
    }

    // ---- cohort de-phase: second resident cohort starts ~half a pass late
    if (blockIdx.x & 256) {
        unsigned long long t0 = __builtin_amdgcn_s_memrealtime();
        while (__builtin_amdgcn_s_memrealtime() - t0 < 64ULL) { }
    }

    // ---------------- build role ----------------
    const int j0 = blockIdx.x * 2;
    const int t = tid;

    // zero-init BOTH buffers (required by depth-0 sparse perms) + sig table
#pragma unroll
    for (int b = 0; b < 2; ++b)
#pragma unroll
        for (int v = 0; v < 2; ++v)
#pragma unroll
            for (int e = 0; e < 2; ++e)
                buf[b][v][tid + e * TBW] = make_float2(0.0f, 0.0f);
    if (tid < 54) sig[tid] = 1.0f / (1.0f + __expf(-logits[tid]));
    __syncthreads();
    if (tid < 2) buf[0][tid][j0 + tid] = make_float2(1.0f, 0.0f);
    __syncthreads();

    int sb = 0;
    for (int d = 0; d < 2; ++d) {
        // ---- 9 perm passes; s<=128 wave-local barrier-free, s>=256 r12 ----
        for (int jp = 0; jp < 9; ++jp) {
            const int s = 4 << jp;
            const int h = s >> 1;
            const int hh = s >> 2;
            const float p0 = sig[(d * 9 + jp) * 3 + 0];
            const float p1 = sig[(d * 9 + jp) * 3 + 1];
            const float p2 = sig[(d * 9 + jp) * 3 + 2];

            // shared mirror-pair body
            auto permTask = [&](int wt, int base) {
                int tt, tm;
                float psel;
                if (wt < hh) { tt = wt;              tm = h - 1 - wt;  psel = p1; }
                else         { const int u = wt - hh; tt = h + u; tm = s - 1 - u; psel = p2; }

                const int eot = (tt < h) ? (2 * tt) : (2 * (tt - h) + 1);
                const int eom = (tm < h) ? (2 * tm) : (2 * (tm - h) + 1);

#pragma unroll
                for (int v = 0; v < 2; ++v) {
                    const float2* src = buf[sb][v];
                    float2* dst = buf[sb ^ 1][v];

                    const float2 xt = src[base + tt], xet = src[base + eot];
                    const float2 xm = src[base + tm], xem = src[base + eom];
                    float2 yt, ym;
                    yt.x = xt.x + p0 * (xet.x - xt.x);
                    yt.y = xt.y + p0 * (xet.y - xt.y);
                    ym.x = xm.x + p0 * (xem.x - xm.x);
                    ym.y = xm.y + p0 * (xem.y - xm.y);

                    float2 ot, om;
                    ot.x = yt.x + psel * (ym.x - yt.x);
                    ot.y = yt.y + psel * (ym.y - yt.y);
                    om.x = ym.x + psel * (yt.x - ym.x);
                    om.y = ym.y + psel * (yt.y - ym.y);
                    dst[base + tt] = ot;
                    dst[base + tm] = om;
                }
            };

            if (jp <= 5) {
                // ---- s <= 128: one wave owns each 128-chunk (both cols) ----
                const int wv = tid >> 6;
                const int lane = tid & 63;
                if (d == 0) {
                    // sparse: active chunk = the one containing j0 (j0,j0+1 same chunk)
                    if (wv == (j0 >> 7) && lane < h) {
                        permTask(lane, (j0 >> (jp + 2)) << (jp + 2));
                    }
                } else {
                    // dense: 64 tasks per chunk (one per lane)
                    permTask(lane & (h - 1),
                             128 * wv + ((lane >> (jp + 1)) << (jp + 2)));
                }
                // intra-wave ordering only: DS writes retired -> visible to wave
                asm volatile("s_waitcnt lgkmcnt(0)" ::: "memory");
                sb ^= 1;
            } else {
                // ---- s >= 256: original r12 mapping + barrier ----
                // FENCE (r5 bug fix): jp==6 reads across 128-chunks written
                // by OTHER waves in the barrier-free jp<=5 section; those
                // writes must be visible before the reads below.
                if (jp == 6) __syncthreads();

                int w = -1, base = 0;
                if (d == 0) {
                    if (tid < h) {
                        w = tid;
                        base = (j0 >> (jp + 2)) << (jp + 2);
                    }
                } else {
                    w = tid & (h - 1);
                    base = (tid >> (jp + 1)) << (jp + 2);
                }
                if (w >= 0) permTask(w, base);
                __syncthreads();
                sb ^= 1;
            }
        }

        // ---- butterfly passes: 9 paired (k even) + 1 scalar (k=1) ----
        float4 dg4, sb4, sp4;
        {   // preload pass i=0 (k=512, k2=256)
            const float4* Dg4 = (const float4*)(diags + (size_t)((d * 10) * N) * 2);
            const float4* Sb4 = (const float4*)(subd  + (size_t)((d * 10) * N) * 2);
            const float4* Sp4 = (const float4*)(supd  + (size_t)((d * 10) * N) * 2);
            dg4 = Dg4[t];
            sb4 = (t >= 256) ? Sb4[t - 256] : make_float4(0.f, 0.f, 0.f, 0.f);
            sp4 = (t < 256)  ? Sp4[t]       : make_float4(0.f, 0.f, 0.f, 0.f);
        }
        for (int i = 0; i < 9; ++i) {
            const int k = N >> (i + 1);
            const int k2 = k >> 1;

            // prefetch pass i+1 (paired) — issued before LDS reads
            float4 dg4n, sb4n, sp4n;
            if (i < 8) {
                const int kn2 = k2 >> 1;
                const float4* Dg4 = (const float4*)(diags + (size_t)((d * 10 + i + 1) * N) * 2);
                const float4* Sb4 = (const float4*)(subd  + (size_t)((d * 10 + i + 1) * N) * 2);
                const float4* Sp4 = (const float4*)(supd  + (size_t)((d * 10 + i + 1) * N) * 2);
                dg4n = Dg4[t];
                sb4n = (t >= kn2)       ? Sb4[t - kn2] : make_float4(0.f, 0.f, 0.f, 0.f);
                sp4n = (t < 512 - kn2)  ? Sp4[t]       : make_float4(0.f, 0.f, 0.f, 0.f);
            }

            const bool has_sb = (t >= k2);
            const bool has_sp = (t < 512 - k2);
#pragma unroll
            for (int v = 0; v < 2; ++v) {
                const float2* src = buf[sb][v];
                const float4 xv = *(const float4*)(&src[2 * t]);
                float4 o;
                o.x = dg4.x * xv.x - dg4.y * xv.y;
                o.y = dg4.x * xv.y + dg4.y * xv.x;
                o.z = dg4.z * xv.z - dg4.w * xv.w;
                o.w = dg4.z * xv.w + dg4.w * xv.z;
                if (has_sb) {
                    const float4 xs = *(const float4*)(&src[2 * t - k]);
                    o.x += sb4.x * xs.x - sb4.y * xs.y;
                    o.y += sb4.x * xs.y + sb4.y * xs.x;
                    o.z += sb4.z * xs.z - sb4.w * xs.w;
                    o.w += sb4.z * xs.w + sb4.w * xs.z;
                }
                if (has_sp) {
                    const float4 xp = *(const float4*)(&src[2 * t + k]);
                    o.x += sp4.x * xp.x - sp4.y * xp.y;
                    o.y += sp4.x * xp.y + sp4.y * xp.x;
                    o.z += sp4.z * xp.z - sp4.w * xp.w;
                    o.w += sp4.z * xp.w + sp4.w * xp.z;
                }
                *(float4*)(&buf[sb ^ 1][v][2 * t]) = o;
            }
            __syncthreads();
            sb ^= 1;
            if (i < 8) { dg4 = dg4n; sb4 = sb4n; sp4 = sp4n; }
        }
        {   // k = 1 scalar pass
            const float2* Dg = (const float2*)(diags + (size_t)((d * 10 + 9) * N) * 2);
            const float2* Sb = (const float2*)(subd  + (size_t)((d * 10 + 9) * N) * 2);
            const float2* Sp = (const float2*)(supd  + (size_t)((d * 10 + 9) * N) * 2);
            const int i0 = 2 * t, i1 = 2 * t + 1;
            const float2 dg0 = Dg[i0], dg1 = Dg[i1];
            const float2 sb0 = (t >= 1) ? Sb[i0 - 1] : make_float2(0.f, 0.f);
            const float2 sb1 = Sb[i0];
            const float2 sp0 = Sp[i0];
            const float2 sp1 = (t < 511) ? Sp[i1] : make_float2(0.f, 0.f);
#pragma unroll
            for (int v = 0; v < 2; ++v) {
                const float2* src = buf[sb][v];
                const float2 x0 = src[i0], x1 = src[i1];
                float2 o0, o1;
                o0.x = dg0.x * x0.x - dg0.y * x0.y;
                o0.y = dg0.x * x0.y + dg0.y * x0.x;
                o1.x = dg1.x * x1.x - dg1.y * x1.y;
                o1.y = dg1.x * x1.y + dg1.y * x1.x;
                if (t >= 1) {
                    const float2 xs = src[i0 - 1];
                    o0.x += sb0.x * xs.x - sb0.y * xs.y;
                    o0.y += sb0.x * xs.y + sb0.y * xs.x;
                }
                // i1 >= 1 always: sub term for o1 uses src[i0] = x0
                o1.x += sb1.x * x0.x - sb1.y * x0.y;
                o1.y += sb1.x * x0.y + sb1.y * x0.x;
                // i0 < 1023 always: sup term for o0 uses src[i1] = x1
                o0.x += sp0.x * x1.x - sp0.y * x1.y;
                o0.y += sp0.x * x1.y + sp0.y * x1.x;
                if (t < 511) {
                    const float2 xp = src[i1 + 1];
                    o1.x += sp1.x * xp.x - sp1.y * xp.y;
                    o1.y += sp1.x * xp.y + sp1.y * xp.x;
                }
                float4 ow;
                ow.x = o0.x; ow.y = o0.y; ow.z = o1.x; ow.w = o1.y;
                *(float4*)(&buf[sb ^ 1][v][i0]) = ow;
            }
            __syncthreads();
            sb ^= 1;
        }
    }

    // ---- epilogue: scatter-write transposed bf16 directly: Bt[n][j0+v] ----
#pragma unroll
    for (int v = 0; v < 2; ++v)
#pragma unroll
        for (int e = 0; e < 2; ++e) {
            const int idx = tid + e * TBW;
            Bt[(size_t)idx * N + (j0 + v)] = f2bf_rne(buf[sb][v][idx].x);
        }
}

// ---------------------------------------------------------------------------
// GEMM round-14 (best measured config): BM=128 x BN=64, BK=64, serial
// 2-barrier K-loop, grid (32,16)=512 blocks -> 2 blocks/CU, XOR-swizzled LDS.
// ---------------------------------------------------------------------------
typedef __attribute__((ext_vector_type(8))) __bf16 bf16x8;
typedef __attribute__((ext_vector_type(4))) float f32x4;

#define GLB(p) ((const __attribute__((address_space(1))) void*)(p))
#define LDS(p) ((__attribute__((address_space(3))) void*)(p))

__global__ __launch_bounds__(THREADS) void gemm_bf16(
    const unsigned short* __restrict__ A2,  // [B][1024] bf16
    const unsigned short* __restrict__ Bt,  // [1024][1024] bf16
    const float* __restrict__ bias,
    float* __restrict__ out)
{
    __shared__ __align__(16) unsigned short As[128 * 64];   // 16 KB
    __shared__ __align__(16) unsigned short Bs[64 * 64];    // 8 KB

    const int m0 = blockIdx.x * 128;
    const int n0 = blockIdx.y * 64;
    const int tid = threadIdx.x;
    const int wave = tid >> 6, lane = tid & 63;
    const int wm = (wave >> 1) * 64, wn = (wave & 1) * 32;
    const int lrow = lane & 15, q = lane >> 4;
    const int r7 = lrow & 7;

    f32x4 acc[4][2] = {};

    for (int kt = 0; kt < 16; ++kt) {
        const int k0 = kt * 64;
        __syncthreads();  // previous tile fully consumed
        {
            const unsigned short* gA = A2 + (size_t)m0 * N + k0;
            const unsigned short* gB = Bt + (size_t)n0 * N + k0;
#pragma unroll
            for (int r = 0; r < 4; ++r) {           // A: 128 rows x 8 groups
                const int s = r * 256 + tid;
                const int row = s >> 3;
                const int gl = (s & 7) ^ (row & 7);  // XOR-swizzled k-group
                __builtin_amdgcn_global_load_lds(GLB(gA + (size_t)row * N + gl * 8),
                                                 LDS(As + s * 8), 16, 0, 0);
            }
#pragma unroll
            for (int r = 0; r < 2; ++r) {           // B: 64 rows x 8 groups
                const int s = r * 256 + tid;
                const int row = s >> 3;
                const int gl = (s & 7) ^ (row & 7);
                __builtin_amdgcn_global_load_lds(GLB(gB + (size_t)row * N + gl * 8),
                                                 LDS(Bs + s * 8), 16, 0, 0);
            }
        }
        __syncthreads();  // DMA drained -> tile ready

#pragma unroll
        for (int kk = 0; kk < 64; kk += 32) {
            const int pg = ((kk >> 3) + q) ^ r7;  // physical (swizzled) group
            bf16x8 a[4], b[2];
#pragma unroll
            for (int mi = 0; mi < 4; ++mi)
                a[mi] = *(const bf16x8*)(As + (wm + mi * 16 + lrow) * 64 + pg * 8);
#pragma unroll
            for (int ni = 0; ni < 2; ++ni)
                b[ni] = *(const bf16x8*)(Bs + (wn + ni * 16 + lrow) * 64 + pg * 8);
#pragma unroll
            for (int mi = 0; mi < 4; ++mi)
#pragma unroll
                for (int ni = 0; ni < 2; ++ni)
                    acc[mi][ni] = __builtin_amdgcn_mfma_f32_16x16x32_bf16(
                        a[mi], b[ni], acc[mi][ni], 0, 0, 0);
        }
    }

    // epilogue: C/D layout col=lane&15, row=q*4+reg
#pragma unroll
    for (int ni = 0; ni < 2; ++ni) {
        const int col = n0 + wn + ni * 16 + lrow;
        const float bv = bias[col];
#pragma unroll
        for (int mi = 0; mi < 4; ++mi)
#pragma unroll
            for (int r = 0; r < 4; ++r) {
                const int row = m0 + wm + mi * 16 + q * 4 + r;
                out[(size_t)row * N + col] = acc[mi][ni][r] + bv;
            }
    }
}

// ---------------------------------------------------------------------------
extern "C" void kernel_launch(void* const* d_in, const int* in_sizes, int n_in,
                              void* d_out, int out_size, void* d_ws, size_t ws_size,
                              hipStream_t stream) {
    const float* x      = (const float*)d_in[0];
    const float* logits = (const float*)d_in[1];
    const float* diags  = (const float*)d_in[2];
    const float* subd   = (const float*)d_in[3];
    const float* supd   = (const float*)d_in[4];
    const float* bias   = (const float*)d_in[5];
    float* out = (float*)d_out;

    const int B = in_sizes[0] / N;  // 4096

    const size_t off_Bt = 0;                                // Bt: 1024*1024*2 B
    const size_t off_A2 = 2u * 1024 * 1024;
    const size_t need   = off_A2 + (size_t)B * N * 2;       // A2: B*1024*2 B

    if (ws_size >= need && B == 4096) {
        unsigned short* Bt = (unsigned short*)((char*)d_ws + off_Bt);
        unsigned short* A2 = (unsigned short*)((char*)d_ws + off_A2);

        prep_kernel<<<dim3(NB_BUILD + 256), dim3(TBW), 0, stream>>>(
            logits, diags, subd, supd, x, Bt, A2);
        gemm_bf16<<<dim3(B / 128, 16), dim3(THREADS), 0, stream>>>(A2, Bt, bias, out);
    } else {
        trifat_kernel_impl<<<dim3(B), dim3(THREADS), 0, stream>>>(
            x, logits, diags, subd, supd, bias, out, B);
    }
}